// Round 1
// baseline (1843.486 us; speedup 1.0000x reference)
//
#include <hip/hip_runtime.h>
#include <cstdint>
#include <cstddef>

#define N_TOK 2048
#define N_EXP 64
#define TOPK  8
#define DHID  2048
#define DFFN  768
#define CAP   512

typedef short s16x8 __attribute__((ext_vector_type(8)));
typedef float f32x4 __attribute__((ext_vector_type(4)));

// fp32 -> bf16 round-to-nearest (half away), cheap: 1 add + shift per elem
__device__ __forceinline__ unsigned pk_bf2(float a, float b) {
    unsigned ua = __float_as_uint(a) + 0x8000u;
    unsigned ub = __float_as_uint(b) + 0x8000u;
    return (ua >> 16) | (ub & 0xffff0000u);
}
__device__ __forceinline__ unsigned short f2bf(float a) {
    return (unsigned short)((__float_as_uint(a) + 0x8000u) >> 16);
}

// ---------------- init: zero out + counters ----------------
__global__ __launch_bounds__(256) void k_init(float4* __restrict__ out4, int* __restrict__ counts) {
    int idx = blockIdx.x * 256 + threadIdx.x;
    const int total = (N_TOK * DHID) / 4;
    for (int i = idx; i < total; i += gridDim.x * 256)
        out4[i] = make_float4(0.f, 0.f, 0.f, 0.f);
    if (idx < N_EXP) counts[idx] = 0;
}

// ---------------- gating: fp32 logits, softmax, top-8, dispatch ----------------
__global__ __launch_bounds__(256) void k_gate(const float* __restrict__ x,
                                              const float* __restrict__ gw,
                                              int* __restrict__ counts,
                                              int* __restrict__ btok,
                                              float* __restrict__ bscore) {
    __shared__ __align__(16) float xs[4][DHID];   // 32 KB
    int t = threadIdx.x;
    int tok0 = blockIdx.x * 4;
    for (int r = 0; r < 4; ++r) {
        const float4* src = (const float4*)(x + (size_t)(tok0 + r) * DHID);
        float4* dst = (float4*)xs[r];
        for (int i = t; i < DHID / 4; i += 256) dst[i] = src[i];
    }
    __syncthreads();
    int w = t >> 6, lane = t & 63;
    int tok = tok0 + w;
    const float4* grow = (const float4*)(gw + (size_t)lane * DHID);
    const float4* xr = (const float4*)xs[w];
    float acc = 0.f;
    #pragma unroll 4
    for (int i = 0; i < DHID / 4; ++i) {
        float4 a = xr[i], b = grow[i];
        acc += a.x * b.x + a.y * b.y + a.z * b.z + a.w * b.w;
    }
    // softmax over 64 lanes (lane = expert)
    float m = acc;
    for (int o = 32; o > 0; o >>= 1) m = fmaxf(m, __shfl_xor(m, o));
    float ex = expf(acc - m);
    float sum = ex;
    for (int o = 32; o > 0; o >>= 1) sum += __shfl_xor(sum, o);
    float p = ex / sum;
    // iterative top-8 with lowest-index tiebreak (matches jax.lax.top_k)
    float pv = p;
    for (int k = 0; k < TOPK; ++k) {
        float mx = pv;
        for (int o = 32; o > 0; o >>= 1) mx = fmaxf(mx, __shfl_xor(mx, o));
        unsigned long long sel = __ballot(pv == mx);
        int who = __ffsll(sel) - 1;
        if (lane == who) {
            pv = -1.f;
            int pos = atomicAdd(&counts[lane], 1);
            if (pos < CAP) {                       // capacity drop, like reference
                btok[lane * CAP + pos] = tok;
                bscore[lane * CAP + pos] = p;
            }
        }
    }
}

// ---------------- gate/up GEMM + SwiGLU -> h (bf16) ----------------
// block = (f_chunk 64, expert). M-tile 128, BK 64. Weights fetched from HBM once.
__global__ __launch_bounds__(256) void k_gateup(const float* __restrict__ x,
                                                const float* __restrict__ wg,
                                                const float* __restrict__ wu,
                                                const int* __restrict__ counts,
                                                const int* __restrict__ btok,
                                                const float* __restrict__ bscore,
                                                unsigned short* __restrict__ h) {
    int e = blockIdx.y;
    int f0 = blockIdx.x * 64;
    int cnt = counts[e]; cnt = cnt > CAP ? CAP : cnt;
    if (cnt == 0) return;

    __shared__ unsigned short Xs[128][72];  // +8 pad: conflict-free b128
    __shared__ unsigned short Gs[64][72];
    __shared__ unsigned short Us[64][72];
    __shared__ float Ss[128];
    __shared__ int   Ts[128];

    int t = threadIdx.x;
    int w = t >> 6, lane = t & 63;
    int wm = w & 1, wf = w >> 1;            // 2x2 wave tiling: M-half, F-half
    int row = lane & 15, quad = lane >> 4;
    int sr = t >> 1, sq = t & 1;            // X staging: 1 row / 2 threads
    int sr4 = t >> 2, sq4 = t & 3;          // W staging: 1 row / 4 threads

    const size_t wbase = ((size_t)e * DFFN + f0) * DHID;

    for (int m0 = 0; m0 < cnt; m0 += 128) {
        __syncthreads();
        if (t < 128) {
            int slot = m0 + t;
            if (slot < cnt) { Ts[t] = btok[e * CAP + slot]; Ss[t] = bscore[e * CAP + slot]; }
            else            { Ts[t] = -1;                   Ss[t] = 0.f; }
        }
        __syncthreads();

        f32x4 accg[4][2], accu[4][2];
        #pragma unroll
        for (int mi = 0; mi < 4; ++mi)
            #pragma unroll
            for (int fi = 0; fi < 2; ++fi) {
                accg[mi][fi] = f32x4{0.f, 0.f, 0.f, 0.f};
                accu[mi][fi] = f32x4{0.f, 0.f, 0.f, 0.f};
            }

        for (int k0 = 0; k0 < DHID; k0 += 64) {
            // ---- stage X[128][64] fp32->bf16 (gathered token rows; pad rows = 0)
            {
                int tokr = Ts[sr];
                if (tokr >= 0) {
                    const float4* src = (const float4*)(x + (size_t)tokr * DHID + k0 + sq * 32);
                    #pragma unroll
                    for (int i = 0; i < 4; ++i) {
                        float4 v0 = src[2 * i], v1 = src[2 * i + 1];
                        uint4 o;
                        o.x = pk_bf2(v0.x, v0.y); o.y = pk_bf2(v0.z, v0.w);
                        o.z = pk_bf2(v1.x, v1.y); o.w = pk_bf2(v1.z, v1.w);
                        *(uint4*)&Xs[sr][sq * 32 + i * 8] = o;
                    }
                } else {
                    uint4 z = make_uint4(0u, 0u, 0u, 0u);
                    #pragma unroll
                    for (int i = 0; i < 4; ++i) *(uint4*)&Xs[sr][sq * 32 + i * 8] = z;
                }
            }
            // ---- stage Wg, Wu [64][64] fp32->bf16
            {
                const float4* gs = (const float4*)(wg + wbase + (size_t)sr4 * DHID + k0) + sq4 * 4;
                const float4* us = (const float4*)(wu + wbase + (size_t)sr4 * DHID + k0) + sq4 * 4;
                #pragma unroll
                for (int i = 0; i < 2; ++i) {
                    float4 v0 = gs[2 * i], v1 = gs[2 * i + 1];
                    uint4 o;
                    o.x = pk_bf2(v0.x, v0.y); o.y = pk_bf2(v0.z, v0.w);
                    o.z = pk_bf2(v1.x, v1.y); o.w = pk_bf2(v1.z, v1.w);
                    *(uint4*)&Gs[sr4][sq4 * 16 + i * 8] = o;
                }
                #pragma unroll
                for (int i = 0; i < 2; ++i) {
                    float4 v0 = us[2 * i], v1 = us[2 * i + 1];
                    uint4 o;
                    o.x = pk_bf2(v0.x, v0.y); o.y = pk_bf2(v0.z, v0.w);
                    o.z = pk_bf2(v1.x, v1.y); o.w = pk_bf2(v1.z, v1.w);
                    *(uint4*)&Us[sr4][sq4 * 16 + i * 8] = o;
                }
            }
            __syncthreads();
            #pragma unroll
            for (int kf = 0; kf < 2; ++kf) {
                s16x8 a[4];
                #pragma unroll
                for (int mi = 0; mi < 4; ++mi)
                    a[mi] = *(const s16x8*)&Xs[wm * 64 + mi * 16 + row][kf * 32 + quad * 8];
                #pragma unroll
                for (int fi = 0; fi < 2; ++fi) {
                    s16x8 bg = *(const s16x8*)&Gs[wf * 32 + fi * 16 + row][kf * 32 + quad * 8];
                    s16x8 bu = *(const s16x8*)&Us[wf * 32 + fi * 16 + row][kf * 32 + quad * 8];
                    #pragma unroll
                    for (int mi = 0; mi < 4; ++mi) {
                        accg[mi][fi] = __builtin_amdgcn_mfma_f32_16x16x32_bf16(a[mi], bg, accg[mi][fi], 0, 0, 0);
                        accu[mi][fi] = __builtin_amdgcn_mfma_f32_16x16x32_bf16(a[mi], bu, accu[mi][fi], 0, 0, 0);
                    }
                }
            }
            __syncthreads();
        }
        // ---- epilogue: h = silu(g)*u*score, bf16 (pad rows -> 0)
        #pragma unroll
        for (int mi = 0; mi < 4; ++mi)
            #pragma unroll
            for (int fi = 0; fi < 2; ++fi)
                #pragma unroll
                for (int r = 0; r < 4; ++r) {
                    int sl = wm * 64 + mi * 16 + quad * 4 + r;
                    float g = accg[mi][fi][r], u = accu[mi][fi][r];
                    float hv = g * (1.f / (1.f + __expf(-g))) * u * Ss[sl];
                    size_t slot = (size_t)(m0 + sl);
                    h[((size_t)e * CAP + slot) * DFFN + f0 + wf * 32 + fi * 16 + row] = f2bf(hv);
                }
    }
}

// ---------------- down GEMM + weighted scatter-add combine ----------------
__global__ __launch_bounds__(256) void k_down(const unsigned short* __restrict__ h,
                                              const float* __restrict__ wd,
                                              const int* __restrict__ counts,
                                              const int* __restrict__ btok,
                                              float* __restrict__ out) {
    int e = blockIdx.y;
    int d0 = blockIdx.x * 64;
    int cnt = counts[e]; cnt = cnt > CAP ? CAP : cnt;
    if (cnt == 0) return;

    __shared__ unsigned short Hs[128][72];
    __shared__ unsigned short Ws[64][72];
    __shared__ int Ts[128];

    int t = threadIdx.x;
    int w = t >> 6, lane = t & 63;
    int wm = w & 1, wdh = w >> 1;
    int row = lane & 15, quad = lane >> 4;
    int sr = t >> 1, sq = t & 1;
    int sr4 = t >> 2, sq4 = t & 3;

    const size_t wbase = ((size_t)e * DHID + d0) * DFFN;

    for (int m0 = 0; m0 < cnt; m0 += 128) {
        __syncthreads();
        if (t < 128) {
            int slot = m0 + t;
            Ts[t] = (slot < cnt) ? btok[e * CAP + slot] : -1;
        }
        __syncthreads();

        f32x4 acc[4][2];
        #pragma unroll
        for (int mi = 0; mi < 4; ++mi)
            #pragma unroll
            for (int di = 0; di < 2; ++di)
                acc[mi][di] = f32x4{0.f, 0.f, 0.f, 0.f};

        for (int k0 = 0; k0 < DFFN; k0 += 64) {
            // ---- stage H (already bf16, pads were written as zeros)
            {
                const uint4* hsrc = (const uint4*)(h + ((size_t)e * CAP + (m0 + sr)) * DFFN + k0 + sq * 32);
                #pragma unroll
                for (int i = 0; i < 4; ++i)
                    *(uint4*)&Hs[sr][sq * 32 + i * 8] = hsrc[i];
            }
            // ---- stage Wd fp32->bf16
            {
                const float4* dsrc = (const float4*)(wd + wbase + (size_t)sr4 * DFFN + k0) + sq4 * 4;
                #pragma unroll
                for (int i = 0; i < 2; ++i) {
                    float4 v0 = dsrc[2 * i], v1 = dsrc[2 * i + 1];
                    uint4 o;
                    o.x = pk_bf2(v0.x, v0.y); o.y = pk_bf2(v0.z, v0.w);
                    o.z = pk_bf2(v1.x, v1.y); o.w = pk_bf2(v1.z, v1.w);
                    *(uint4*)&Ws[sr4][sq4 * 16 + i * 8] = o;
                }
            }
            __syncthreads();
            #pragma unroll
            for (int kf = 0; kf < 2; ++kf) {
                s16x8 a[4];
                #pragma unroll
                for (int mi = 0; mi < 4; ++mi)
                    a[mi] = *(const s16x8*)&Hs[wm * 64 + mi * 16 + row][kf * 32 + quad * 8];
                #pragma unroll
                for (int di = 0; di < 2; ++di) {
                    s16x8 b = *(const s16x8*)&Ws[wdh * 32 + di * 16 + row][kf * 32 + quad * 8];
                    #pragma unroll
                    for (int mi = 0; mi < 4; ++mi)
                        acc[mi][di] = __builtin_amdgcn_mfma_f32_16x16x32_bf16(a[mi], b, acc[mi][di], 0, 0, 0);
                }
            }
            __syncthreads();
        }
        // ---- combine: atomicAdd (score already folded into h)
        #pragma unroll
        for (int mi = 0; mi < 4; ++mi)
            #pragma unroll
            for (int di = 0; di < 2; ++di)
                #pragma unroll
                for (int r = 0; r < 4; ++r) {
                    int sl = wm * 64 + mi * 16 + quad * 4 + r;
                    int tok = Ts[sl];
                    if (tok >= 0)
                        atomicAdd(out + (size_t)tok * DHID + d0 + wdh * 32 + di * 16 + row,
                                  acc[mi][di][r]);
                }
    }
}

extern "C" void kernel_launch(void* const* d_in, const int* in_sizes, int n_in,
                              void* d_out, int out_size, void* d_ws, size_t ws_size,
                              hipStream_t stream) {
    const float* x  = (const float*)d_in[0];   // [1,2048,2048]
    const float* gw = (const float*)d_in[1];   // [64,2048]
    const float* wg = (const float*)d_in[2];   // [64,768,2048]
    const float* wu = (const float*)d_in[3];   // [64,768,2048]
    const float* wd = (const float*)d_in[4];   // [64,2048,768]
    float* out = (float*)d_out;

    char* ws = (char*)d_ws;
    int*   counts = (int*)ws;                         // 64 ints
    int*   btok   = (int*)(ws + 4096);                // [64][512]
    float* bscore = (float*)(ws + 4096 + 131072);     // [64][512]
    unsigned short* h = (unsigned short*)(ws + (1 << 20)); // [64][512][768] bf16, 48 MB

    hipLaunchKernelGGL(k_init,   dim3(2048),   dim3(256), 0, stream, (float4*)out, counts);
    hipLaunchKernelGGL(k_gate,   dim3(N_TOK/4), dim3(256), 0, stream, x, gw, counts, btok, bscore);
    hipLaunchKernelGGL(k_gateup, dim3(12, 64), dim3(256), 0, stream, x, wg, wu, counts, btok, bscore, h);
    hipLaunchKernelGGL(k_down,   dim3(32, 64), dim3(256), 0, stream, h, wd, counts, btok, out);
}